// Round 17
// baseline (73.881 us; speedup 1.0000x reference)
//
#include <hip/hip_runtime.h>
#include <hip/hip_bf16.h>

// Grid_INR2D round 17: round-14 body + batch-split via SCALAR pointer bump.
//  r15 (extra streams, clean 76-VGPR codegen) and r16 (coalesced staging)
//  both neutral -> limiter is whole-block latency serialization: grid 1024
//  == residency capacity (4 blocks/CU x 256 CU), ZERO queued blocks, so
//  dur = slowest block's full serial time (prologue + 8 chains).
//  r10 tested batch-split but folded b0 into PER-LANE address math -> VGPR
//  growth -> allocator collapse. This version bumps the feat/out POINTERS
//  with blockIdx.y in pure SGPR arithmetic (s_lshl+s_add, zero VGPR delta);
//  body uses literal batch indices 0..3 -> addressing byte-identical to r14.
//  grid (1024,2) = 2048 blocks: 4 resident + 4 queued per CU. Cost: the
//  sampling/staging prologue runs 2x per pixel (grid reads L2/L3-served).
//  GATES: VGPR 96..128 & WRITE 6144KB (64/48 + WRITE>>7MB = collapse ->
//  revert to round-14 source as final); absmax exactly 0.0078125.
// Fragment identity (validated rounds 3-16):
//   A: row=lane&15, k=4*(lane>>4)+(e&3)+16*(e>>2); B: col=lane&15, same k;
//   C/D: col=lane&15, row=4*(lane>>4)+reg  ==> C-frag of layer n is B-frag
//   of layer n+1 per-lane: B[kb].e = bf16(relu(C[2kb+(e>=4)].reg[e&3])).

typedef float f32x4 __attribute__((ext_vector_type(4)));
typedef short s16x8 __attribute__((ext_vector_type(8)));

#define MFMA16(a, b, c) __builtin_amdgcn_mfma_f32_16x16x32_bf16((a), (b), (c), 0, 0, 0)

__device__ __forceinline__ short bfbits(float f) {   // RNE via HW cvt
    return __builtin_bit_cast(short, __float2bfloat16(f));
}

__device__ __forceinline__ s16x8 pack_relu(const f32x4 lo, const f32x4 hi) {
    s16x8 r;
#pragma unroll
    for (int e = 0; e < 4; ++e) {
        r[e]     = bfbits(fmaxf(lo[e], 0.0f));
        r[e + 4] = bfbits(fmaxf(hi[e], 0.0f));
    }
    return r;
}

// LDS frag table: fid 0..11 = w1[mt*3+kb], 12..19 = w2[mt*2+kb], 20..21 = w3[kb]
#define NFRAG 22

__global__ __launch_bounds__(256, 4) void grid_inr_mfma(
    const float* __restrict__ feat0,
    const float* __restrict__ g0, const float* __restrict__ g1,
    const float* __restrict__ g2, const float* __restrict__ g3,
    const float* __restrict__ w1, const float* __restrict__ b1,
    const float* __restrict__ w2, const float* __restrict__ b2,
    const float* __restrict__ w3, const float* __restrict__ b3,
    float* __restrict__ out0)
{
    __shared__ __align__(16) short lds_w[NFRAG * 64 * 8];

    // ---- batch-slice pointer bump: pure SGPR math, zero VGPR delta --------
    // slice y handles batches 4y..4y+3: feat += y*4*32*65536 = y<<23 floats,
    // out += y*4*3*65536 floats. Body below uses literal batches 0..3.
    const float* feat = feat0 + ((size_t)blockIdx.y << 23);
    float*       out  = out0  + ((size_t)blockIdx.y * (4 * 3 * 65536));

    const int lane  = threadIdx.x & 63;
    const int col   = lane & 15;    // A row / B col / pixel-in-tile
    const int lrow  = lane >> 4;    // k-group
    const int wv    = threadIdx.x >> 6;
    const int p     = blockIdx.x * 64 + wv * 16 + col;   // this lane's pixel

    // ---------------- stage weight A-frags into LDS (once per block) -------
    {
        const int cs = lane, c15 = lane & 15, r4 = lane >> 4;
#pragma unroll 1
        for (int fid = threadIdx.x >> 6; fid < NFRAG; fid += 4) {
            const float* src;
            if (fid < 12) {
                const int mt = fid / 3, kb = fid - 3 * mt;
                src = w1 + (16 * mt + c15) * 96 + 32 * kb + 4 * r4;
            } else if (fid < 20) {
                const int f = fid - 12, mt = f >> 1, kb = f & 1;
                src = w2 + (16 * mt + c15) * 64 + 32 * kb + 4 * r4;
            } else {
                const int kb = fid - 20;
                const int row3 = (c15 < 3) ? c15 : 2;   // junk rows unused
                src = w3 + row3 * 64 + 32 * kb + 4 * r4;
            }
            s16x8 frag;
#pragma unroll
            for (int e = 0; e < 8; ++e)
                frag[e] = bfbits(src[(e & 3) + 16 * (e >> 2)]);
            *(s16x8*)&lds_w[(fid * 64 + cs) * 8] = frag;
        }
    }

    // ---------------- biases in regs (f32, per-lane rows) -------------------
    f32x4 b1f[4], b2f[4];
#pragma unroll
    for (int mt = 0; mt < 4; ++mt) {
        b1f[mt] = *(const f32x4*)(b1 + 16 * mt + 4 * lrow);
        b2f[mt] = *(const f32x4*)(b2 + 16 * mt + 4 * lrow);
    }
    const float b3s0 = b3[0], b3s1 = b3[1], b3s2 = b3[2];  // uniform s_loads

    // ---------------- grid-sample -> localB[2] (B-frags, k=local ch) --------
    s16x8 localB[2];
    {
        const float* gs[4] = {g0, g1, g2, g3};
        const int    gn[4] = {32, 64, 128, 256};
        const int px = p & 255;
        const int py = p >> 8;
#pragma unroll
        for (int lv = 0; lv < 4; ++lv) {
            const int G = gn[lv];
            const float ix = (float)((2 * px + 1) * (G - 1)) * (1.0f / 512.0f);
            const float iy = (float)((2 * py + 1) * (G - 1)) * (1.0f / 512.0f);
            int ix0 = (int)ix;
            int iy0 = (int)iy;
            if (ix0 > G - 1) ix0 = G - 1;
            if (iy0 > G - 1) iy0 = G - 1;
            const int ix1 = (ix0 + 1 < G - 1) ? (ix0 + 1) : (G - 1);
            const int iy1 = (iy0 + 1 < G - 1) ? (iy0 + 1) : (G - 1);
            const float wx = ix - (float)ix0;
            const float wy = iy - (float)iy0;
            const float w00 = (1.0f - wy) * (1.0f - wx);
            const float w01 = (1.0f - wy) * wx;
            const float w10 = wy * (1.0f - wx);
            const float w11 = wy * wx;
            const int o00 = iy0 * G + ix0;
            const int o01 = iy0 * G + ix1;
            const int o10 = iy1 * G + ix0;
            const int o11 = iy1 * G + ix1;
            const float* g = gs[lv];
            const int GG = G * G;
#pragma unroll
            for (int j = 0; j < 4; ++j) {
                const float* gc = g + (4 * lrow + j) * GG;
                const float v = gc[o00] * w00 + gc[o01] * w01 +
                                gc[o10] * w10 + gc[o11] * w11;
                localB[lv >> 1][(lv & 1) * 4 + j] = bfbits(v);
            }
        }
    }

    __syncthreads();   // LDS frag table ready

    const short* lw = lds_w + lane * 8;      // per-lane base; fid via offset
#define LDSFRAG(fid) (*(const s16x8*)(lw + (fid) * 64 * 8))

    // ---- register-cache small frag groups; hoist batch-invariant layer-1 ---
    s16x8 w1ff[4], w3f[2];
#pragma unroll
    for (int mt = 0; mt < 4; ++mt) w1ff[mt] = LDSFRAG(mt * 3);
    w3f[0] = LDSFRAG(20);
    w3f[1] = LDSFRAG(21);

    // c1base[mt] = b1 + W1[:,32:96] . local   (batch-invariant, once)
    f32x4 c1base[4];
#pragma unroll
    for (int mt = 0; mt < 4; ++mt) {
        c1base[mt] = b1f[mt];
        c1base[mt] = MFMA16(LDSFRAG(mt * 3 + 1), localB[0], c1base[mt]);
        c1base[mt] = MFMA16(LDSFRAG(mt * 3 + 2), localB[1], c1base[mt]);
    }

    // ---- per-batch MLP body (b is a LITERAL 0..3 within this slice) --------
    auto process = [&](int b, const s16x8 ff) {
        f32x4 c1[4];
#pragma unroll
        for (int mt = 0; mt < 4; ++mt)
            c1[mt] = MFMA16(w1ff[mt], ff, c1base[mt]);

        s16x8 h1b0 = pack_relu(c1[0], c1[1]);
        s16x8 h1b1 = pack_relu(c1[2], c1[3]);

        f32x4 c2[4];
#pragma unroll
        for (int mt = 0; mt < 4; ++mt) {
            c2[mt] = b2f[mt];
            c2[mt] = MFMA16(LDSFRAG(12 + mt * 2),     h1b0, c2[mt]);
            c2[mt] = MFMA16(LDSFRAG(12 + mt * 2 + 1), h1b1, c2[mt]);
        }
        s16x8 h2b0 = pack_relu(c2[0], c2[1]);
        s16x8 h2b1 = pack_relu(c2[2], c2[3]);

        f32x4 c3 = {0.f, 0.f, 0.f, 0.f};
        c3 = MFMA16(w3f[0], h2b0, c3);
        c3 = MFMA16(w3f[1], h2b1, c3);

        if (lrow == 0) {
            out[((b * 3 + 0) << 16) + p] = c3[0] + b3s0;
            out[((b * 3 + 1) << 16) + p] = c3[1] + b3s1;
            out[((b * 3 + 2) << 16) + p] = c3[2] + b3s2;
        }
    };

    // ---- batch loop: 4 batches (2 pairs), 2-deep ping-pong prefetch --------
    float rawP[8], rawQ[8];
#pragma unroll
    for (int e = 0; e < 8; ++e) {
        const int fc = 4 * lrow + (e & 3) + 16 * (e >> 2);
        rawP[e] = feat[(fc << 16) + p];          // slice-batch 0
        rawQ[e] = feat[((32 + fc) << 16) + p];   // slice-batch 1
    }

#pragma unroll 1
    for (int bp = 0; bp < 2; ++bp) {
        // batch A = 2*bp (from rawP); refill rawP with batch 2*bp+2
        s16x8 ff;
#pragma unroll
        for (int e = 0; e < 8; ++e) ff[e] = bfbits(rawP[e]);
        if (bp < 1) {
#pragma unroll
            for (int e = 0; e < 8; ++e) {
                const int fc = 4 * lrow + (e & 3) + 16 * (e >> 2);
                rawP[e] = feat[((((2 * bp + 2) << 5) | fc) << 16) + p];
            }
        }
        process(2 * bp, ff);

        // batch B = 2*bp+1 (from rawQ); refill rawQ with batch 2*bp+3
#pragma unroll
        for (int e = 0; e < 8; ++e) ff[e] = bfbits(rawQ[e]);
        if (bp < 1) {
#pragma unroll
            for (int e = 0; e < 8; ++e) {
                const int fc = 4 * lrow + (e & 3) + 16 * (e >> 2);
                rawQ[e] = feat[((((2 * bp + 3) << 5) | fc) << 16) + p];
            }
        }
        process(2 * bp + 1, ff);
    }
#undef LDSFRAG
}

extern "C" void kernel_launch(void* const* d_in, const int* in_sizes, int n_in,
                              void* d_out, int out_size, void* d_ws, size_t ws_size,
                              hipStream_t stream) {
    const float* feat = (const float*)d_in[0];
    const float* g0   = (const float*)d_in[1];
    const float* g1   = (const float*)d_in[2];
    const float* g2   = (const float*)d_in[3];
    const float* g3   = (const float*)d_in[4];
    const float* w1   = (const float*)d_in[5];
    const float* b1   = (const float*)d_in[6];
    const float* w2   = (const float*)d_in[7];
    const float* b2   = (const float*)d_in[8];
    const float* w3   = (const float*)d_in[9];
    const float* b3   = (const float*)d_in[10];

    // x: 65536 px / 64 px-per-block = 1024;  y: 2 batch-slices (4 b each).
    // 2048 blocks -> 4 resident + 4 queued per CU; slice offset in SGPRs.
    dim3 grid(1024, 2);
    grid_inr_mfma<<<grid, 256, 0, stream>>>(
        feat, g0, g1, g2, g3, w1, b1, w2, b2, w3, b3, (float*)d_out);
}

// Round 18
// 28.609 us; speedup vs baseline: 2.5824x; 2.5824x over previous
//
#include <hip/hip_runtime.h>
#include <hip/hip_bf16.h>

// Grid_INR2D FINAL (round 18 = round 6/14 verbatim, 28.8us verified twice).
//  Fused single kernel: bf16-MFMA chain, pre-swizzled LDS weight-frag table,
//  batch-invariant c1base hoist, w1-feat/w3 reg-cached, 2-deep feat
//  prefetch, (256,4), 1024 blocks x 8 batches.
//  17-round search summary: 11 structural experiments, all regressed or
//  neutral. 7 register-allocator collapses (ILP/pipeline/occupancy/split
//  variants AND a pure-SGPR pointer-bump batch-split, r17) -- the body sits
//  on a codegen knife-edge; any source perturbation tips the gfx950
//  allocator into spill collapse (VGPR 64/48/40/32 + 10-100MB scratch).
//  Clean-codegen probes: 2-stream ILP @76 VGPR (r15, +0.7us), coalesced
//  staging (r16, neutral) -> neither streams nor staging BW is the limiter.
//  Kernel-fission probes (r12/r13): overhead > TLP gain.
//  Floor analysis: latency-bound at 28.8us (MfmaUtil ~8%, VALUBusy ~30%,
//  HBM ~26%); hiding the remaining dependency latency requires in-flight
//  state / restructures the allocator will not grant at HIP source level.
// Fragment identity (validated rounds 3-17):
//   A: row=lane&15, k=4*(lane>>4)+(e&3)+16*(e>>2); B: col=lane&15, same k;
//   C/D: col=lane&15, row=4*(lane>>4)+reg  ==> C-frag of layer n is B-frag
//   of layer n+1 per-lane: B[kb].e = bf16(relu(C[2kb+(e>=4)].reg[e&3])).

typedef float f32x4 __attribute__((ext_vector_type(4)));
typedef short s16x8 __attribute__((ext_vector_type(8)));

#define MFMA16(a, b, c) __builtin_amdgcn_mfma_f32_16x16x32_bf16((a), (b), (c), 0, 0, 0)

__device__ __forceinline__ short bfbits(float f) {   // RNE via HW cvt
    return __builtin_bit_cast(short, __float2bfloat16(f));
}

__device__ __forceinline__ s16x8 pack_relu(const f32x4 lo, const f32x4 hi) {
    s16x8 r;
#pragma unroll
    for (int e = 0; e < 4; ++e) {
        r[e]     = bfbits(fmaxf(lo[e], 0.0f));
        r[e + 4] = bfbits(fmaxf(hi[e], 0.0f));
    }
    return r;
}

// LDS frag table: fid 0..11 = w1[mt*3+kb], 12..19 = w2[mt*2+kb], 20..21 = w3[kb]
#define NFRAG 22

__global__ __launch_bounds__(256, 4) void grid_inr_mfma(
    const float* __restrict__ feat,
    const float* __restrict__ g0, const float* __restrict__ g1,
    const float* __restrict__ g2, const float* __restrict__ g3,
    const float* __restrict__ w1, const float* __restrict__ b1,
    const float* __restrict__ w2, const float* __restrict__ b2,
    const float* __restrict__ w3, const float* __restrict__ b3,
    float* __restrict__ out)
{
    __shared__ __align__(16) short lds_w[NFRAG * 64 * 8];

    const int lane  = threadIdx.x & 63;
    const int col   = lane & 15;    // A row / B col / pixel-in-tile
    const int lrow  = lane >> 4;    // k-group
    const int wv    = threadIdx.x >> 6;
    const int p     = blockIdx.x * 64 + wv * 16 + col;   // this lane's pixel

    // ---------------- stage weight A-frags into LDS (once per block) -------
    {
        const int cs = lane, c15 = lane & 15, r4 = lane >> 4;
#pragma unroll 1
        for (int fid = threadIdx.x >> 6; fid < NFRAG; fid += 4) {
            const float* src;
            if (fid < 12) {
                const int mt = fid / 3, kb = fid - 3 * mt;
                src = w1 + (16 * mt + c15) * 96 + 32 * kb + 4 * r4;
            } else if (fid < 20) {
                const int f = fid - 12, mt = f >> 1, kb = f & 1;
                src = w2 + (16 * mt + c15) * 64 + 32 * kb + 4 * r4;
            } else {
                const int kb = fid - 20;
                const int row3 = (c15 < 3) ? c15 : 2;   // junk rows unused
                src = w3 + row3 * 64 + 32 * kb + 4 * r4;
            }
            s16x8 frag;
#pragma unroll
            for (int e = 0; e < 8; ++e)
                frag[e] = bfbits(src[(e & 3) + 16 * (e >> 2)]);
            *(s16x8*)&lds_w[(fid * 64 + cs) * 8] = frag;
        }
    }

    // ---------------- biases in regs (f32, per-lane rows) -------------------
    f32x4 b1f[4], b2f[4];
#pragma unroll
    for (int mt = 0; mt < 4; ++mt) {
        b1f[mt] = *(const f32x4*)(b1 + 16 * mt + 4 * lrow);
        b2f[mt] = *(const f32x4*)(b2 + 16 * mt + 4 * lrow);
    }
    const float b3s0 = b3[0], b3s1 = b3[1], b3s2 = b3[2];  // uniform s_loads

    // ---------------- grid-sample -> localB[2] (B-frags, k=local ch) --------
    s16x8 localB[2];
    {
        const float* gs[4] = {g0, g1, g2, g3};
        const int    gn[4] = {32, 64, 128, 256};
        const int px = p & 255;
        const int py = p >> 8;
#pragma unroll
        for (int lv = 0; lv < 4; ++lv) {
            const int G = gn[lv];
            const float ix = (float)((2 * px + 1) * (G - 1)) * (1.0f / 512.0f);
            const float iy = (float)((2 * py + 1) * (G - 1)) * (1.0f / 512.0f);
            int ix0 = (int)ix;
            int iy0 = (int)iy;
            if (ix0 > G - 1) ix0 = G - 1;
            if (iy0 > G - 1) iy0 = G - 1;
            const int ix1 = (ix0 + 1 < G - 1) ? (ix0 + 1) : (G - 1);
            const int iy1 = (iy0 + 1 < G - 1) ? (iy0 + 1) : (G - 1);
            const float wx = ix - (float)ix0;
            const float wy = iy - (float)iy0;
            const float w00 = (1.0f - wy) * (1.0f - wx);
            const float w01 = (1.0f - wy) * wx;
            const float w10 = wy * (1.0f - wx);
            const float w11 = wy * wx;
            const int o00 = iy0 * G + ix0;
            const int o01 = iy0 * G + ix1;
            const int o10 = iy1 * G + ix0;
            const int o11 = iy1 * G + ix1;
            const float* g = gs[lv];
            const int GG = G * G;
#pragma unroll
            for (int j = 0; j < 4; ++j) {
                const float* gc = g + (4 * lrow + j) * GG;
                const float v = gc[o00] * w00 + gc[o01] * w01 +
                                gc[o10] * w10 + gc[o11] * w11;
                localB[lv >> 1][(lv & 1) * 4 + j] = bfbits(v);
            }
        }
    }

    __syncthreads();   // LDS frag table ready

    const short* lw = lds_w + lane * 8;      // per-lane base; fid via offset
#define LDSFRAG(fid) (*(const s16x8*)(lw + (fid) * 64 * 8))

    // ---- register-cache small frag groups; hoist batch-invariant layer-1 ---
    s16x8 w1ff[4], w3f[2];
#pragma unroll
    for (int mt = 0; mt < 4; ++mt) w1ff[mt] = LDSFRAG(mt * 3);
    w3f[0] = LDSFRAG(20);
    w3f[1] = LDSFRAG(21);

    // c1base[mt] = b1 + W1[:,32:96] . local   (batch-invariant, once)
    f32x4 c1base[4];
#pragma unroll
    for (int mt = 0; mt < 4; ++mt) {
        c1base[mt] = b1f[mt];
        c1base[mt] = MFMA16(LDSFRAG(mt * 3 + 1), localB[0], c1base[mt]);
        c1base[mt] = MFMA16(LDSFRAG(mt * 3 + 2), localB[1], c1base[mt]);
    }

    // ---- per-batch MLP body (b only feeds store addressing) ----------------
    auto process = [&](int b, const s16x8 ff) {
        f32x4 c1[4];
#pragma unroll
        for (int mt = 0; mt < 4; ++mt)
            c1[mt] = MFMA16(w1ff[mt], ff, c1base[mt]);

        s16x8 h1b0 = pack_relu(c1[0], c1[1]);
        s16x8 h1b1 = pack_relu(c1[2], c1[3]);

        f32x4 c2[4];
#pragma unroll
        for (int mt = 0; mt < 4; ++mt) {
            c2[mt] = b2f[mt];
            c2[mt] = MFMA16(LDSFRAG(12 + mt * 2),     h1b0, c2[mt]);
            c2[mt] = MFMA16(LDSFRAG(12 + mt * 2 + 1), h1b1, c2[mt]);
        }
        s16x8 h2b0 = pack_relu(c2[0], c2[1]);
        s16x8 h2b1 = pack_relu(c2[2], c2[3]);

        f32x4 c3 = {0.f, 0.f, 0.f, 0.f};
        c3 = MFMA16(w3f[0], h2b0, c3);
        c3 = MFMA16(w3f[1], h2b1, c3);

        if (lrow == 0) {
            out[((b * 3 + 0) << 16) + p] = c3[0] + b3s0;
            out[((b * 3 + 1) << 16) + p] = c3[1] + b3s1;
            out[((b * 3 + 2) << 16) + p] = c3[2] + b3s2;
        }
    };

    // ---- batch loop: 2-deep feat prefetch via named ping-pong buffers ------
    float rawP[8], rawQ[8];
#pragma unroll
    for (int e = 0; e < 8; ++e) {
        const int fc = 4 * lrow + (e & 3) + 16 * (e >> 2);
        rawP[e] = feat[(fc << 16) + p];          // batch 0
        rawQ[e] = feat[((32 + fc) << 16) + p];   // batch 1
    }

#pragma unroll 1
    for (int bp = 0; bp < 4; ++bp) {
        // batch A = 2*bp (from rawP); refill rawP with batch 2*bp+2
        s16x8 ff;
#pragma unroll
        for (int e = 0; e < 8; ++e) ff[e] = bfbits(rawP[e]);
        if (bp < 3) {
#pragma unroll
            for (int e = 0; e < 8; ++e) {
                const int fc = 4 * lrow + (e & 3) + 16 * (e >> 2);
                rawP[e] = feat[((((2 * bp + 2) << 5) | fc) << 16) + p];
            }
        }
        process(2 * bp, ff);

        // batch B = 2*bp+1 (from rawQ); refill rawQ with batch 2*bp+3
#pragma unroll
        for (int e = 0; e < 8; ++e) ff[e] = bfbits(rawQ[e]);
        if (bp < 3) {
#pragma unroll
            for (int e = 0; e < 8; ++e) {
                const int fc = 4 * lrow + (e & 3) + 16 * (e >> 2);
                rawQ[e] = feat[((((2 * bp + 3) << 5) | fc) << 16) + p];
            }
        }
        process(2 * bp + 1, ff);
    }
#undef LDSFRAG
}

extern "C" void kernel_launch(void* const* d_in, const int* in_sizes, int n_in,
                              void* d_out, int out_size, void* d_ws, size_t ws_size,
                              hipStream_t stream) {
    const float* feat = (const float*)d_in[0];
    const float* g0   = (const float*)d_in[1];
    const float* g1   = (const float*)d_in[2];
    const float* g2   = (const float*)d_in[3];
    const float* g3   = (const float*)d_in[4];
    const float* w1   = (const float*)d_in[5];
    const float* b1   = (const float*)d_in[6];
    const float* w2   = (const float*)d_in[7];
    const float* b2   = (const float*)d_in[8];
    const float* w3   = (const float*)d_in[9];
    const float* b3   = (const float*)d_in[10];

    // 65536 px / (16 px/wave * 4 waves) = 1024 blocks; all 8 batches inside.
    grid_inr_mfma<<<1024, 256, 0, stream>>>(
        feat, g0, g1, g2, g3, w1, b1, w2, b2, w3, b3, (float*)d_out);
}